// Round 1
// baseline (285.837 us; speedup 1.0000x reference)
//
#include <hip/hip_runtime.h>
#include <math.h>

// R7: fused single-pass NoisyTopkRouter.
// Evidence from R6 rocprof: router_main 79.6us with MfmaUtil 12.5%, VALUBusy 11%,
// HBM 13.5%, Occ 37% -> latency/barrier-bound (5900 cyc per chunk for ~60 cyc of
// MFMA work; 2 __syncthreads per chunk serialize all waves). Plus 32 MB zpart
// round-trip + 3-dispatch pipeline overhead (256us total vs 79us max dispatch).
// Fix:
//  - A-fragments built DIRECTLY from global x (lane(col,q) needs 32 contiguous
//    bytes of one token row -> two float4 loads). No LDS, no barriers in K-loop.
//  - B-fragments straight from fragment-ordered wt3 (unchanged prep_w).
//  - 512 blocks x 4 waves, 32 tokens/block, full K=2048, mt=2 per wave.
//    Explicit 1-chunk register double-buffer of A and B.
//  - Epilogue fused: stage 32x128 z-tile in LDS (row padded to 132 -> 2-way,
//    free), one barrier, then verbatim softmax/top8/masked-softmax.
//  - Numerics bit-identical to R6: two accumulator sets (chunks 0-31 / 32-63)
//    with identical per-chunk MFMA chain order, identical fp32 fold
//    (a0 + a1*2^-11) per segment, identical f64 combine, f64 softplus.
// d_ws budget: 1 MB (wt3 only; zpart eliminated).

typedef _Float16 f16x8 __attribute__((ext_vector_type(8)));
typedef float f32x4 __attribute__((ext_vector_type(4)));

constexpr int ND = 2048, NE = 64, NK = 8, NTOK = 16384;
constexpr int KC   = 32;          // k per chunk (one MFMA K)
constexpr int NCHT = ND / KC;     // 64 chunks total
constexpr int KS   = 2;           // numeric K-split ways (kept for bit-exactness)
constexpr int CPS  = NCHT / KS;   // 32 chunks per segment
constexpr int MTOK = 32;          // tokens per block
constexpr int ZROW = 132;         // padded fp32 LDS row (2-way bank aliasing = free)

// ---- prep: W1|W2 -> f16 hi / lo*2^11 planes in MFMA B-fragment order (unchanged).
// Layout: frag(cg, p, t) at ((cg*2+p)*8 + t)*512 + lane*8, cg=0..63 chunk,
// p=plane, t=N-tile (0-3: W1 cols, 4-7: W2 cols), lane=(quad<<4)|col.
__global__ void prep_w(const float* __restrict__ W1, const float* __restrict__ W2,
                       _Float16* __restrict__ wt3) {
    const int g    = blockIdx.x * 256 + threadIdx.x;   // 0..32767
    const int cg   = g >> 9;
    const int rem  = g & 511;
    const int t    = rem >> 6;
    const int lane = rem & 63;
    const int col  = lane & 15, q = lane >> 4;
    const int n    = t * 16 + col;
    const float* W = (t < 4) ? W1 : W2;
    const int cn   = n & 63;
    _Float16 h[8], l[8];
    #pragma unroll
    for (int j = 0; j < 8; ++j) {
        const float v = W[(size_t)(cg * 32 + q * 8 + j) * 64 + cn];
        const _Float16 hh = (_Float16)v;
        h[j] = hh;
        l[j] = (_Float16)((v - (float)hh) * 2048.0f);   // pre-scaled lo plane
    }
    *(f16x8*)&wt3[((size_t)(cg * 2 + 0) * 8 + t) * 512 + lane * 8] = *(f16x8*)h;
    *(f16x8*)&wt3[((size_t)(cg * 2 + 1) * 8 + t) * 512 + lane * 8] = *(f16x8*)l;
}

// split 8 fp32 -> f16 hi plane + (residual*2048) lo plane. Same math as R6.
__device__ __forceinline__ void split8(const float4 a, const float4 b,
                                       f16x8& hh, f16x8& ll) {
    const _Float16 h0 = (_Float16)a.x, h1 = (_Float16)a.y,
                   h2 = (_Float16)a.z, h3 = (_Float16)a.w;
    const _Float16 h4 = (_Float16)b.x, h5 = (_Float16)b.y,
                   h6 = (_Float16)b.z, h7 = (_Float16)b.w;
    hh = (f16x8){h0, h1, h2, h3, h4, h5, h6, h7};
    ll = (f16x8){(_Float16)((a.x - (float)h0) * 2048.0f),
                 (_Float16)((a.y - (float)h1) * 2048.0f),
                 (_Float16)((a.z - (float)h2) * 2048.0f),
                 (_Float16)((a.w - (float)h3) * 2048.0f),
                 (_Float16)((b.x - (float)h4) * 2048.0f),
                 (_Float16)((b.y - (float)h5) * 2048.0f),
                 (_Float16)((b.z - (float)h6) * 2048.0f),
                 (_Float16)((b.w - (float)h7) * 2048.0f)};
}

// ---- fused: GEMM (barrier-free) + softmax/top8/masked-softmax epilogue.
__global__ __launch_bounds__(256, 2)
void router_fused(const float* __restrict__ x, const _Float16* __restrict__ wt3,
                  const float* __restrict__ noise,
                  const float* __restrict__ b1, const float* __restrict__ b2,
                  float* __restrict__ out_sparse, float* __restrict__ out_idx,
                  float* __restrict__ out_full) {
    __shared__ float zs[MTOK * ZROW];   // 16.9 KB
    const int tid  = threadIdx.x;
    const int lane = tid & 63;
    const int wu   = __builtin_amdgcn_readfirstlane(tid >> 6);
    const int col  = lane & 15, q = lane >> 4;
    const long tok0 = (long)blockIdx.x * MTOK;
    const int ta = 2 * wu, tb = 2 * wu + 1;   // this wave's N-tiles

    // A-fragment source rows: lane(col,q) reads x[tok0 + mt*16 + col][c*32 + q*8 ..+7]
    const float* xr0 = x + (tok0 + col)      * (size_t)ND + q * 8;   // mt=0
    const float* xr1 = x + (tok0 + 16 + col) * (size_t)ND + q * 8;   // mt=1
    const _Float16* wl = wt3 + (size_t)lane * 8;

    f32x4 a0[2][2], a1[2][2];   // [mt][i] current-segment accumulators
    f32x4 zk0[2][2];            // segment-0 folded partial (matches R6 zpart ks=0)

    auto zero_acc = [&]() {
        #pragma unroll
        for (int m = 0; m < 2; ++m)
            #pragma unroll
            for (int i = 0; i < 2; ++i)
                #pragma unroll
                for (int r = 0; r < 4; ++r) { a0[m][i][r] = 0.f; a1[m][i][r] = 0.f; }
    };

    // One K segment (CPS chunks), 1-chunk register double-buffer for A and B.
    auto run_seg = [&](const int cbeg) {
        float4 x0a = *(const float4*)(xr0 + (size_t)cbeg * KC);
        float4 x0b = *(const float4*)(xr0 + (size_t)cbeg * KC + 4);
        float4 x1a = *(const float4*)(xr1 + (size_t)cbeg * KC);
        float4 x1b = *(const float4*)(xr1 + (size_t)cbeg * KC + 4);
        const _Float16* w0 = wl + (size_t)cbeg * 8192;   // 2 planes * 8 tiles * 512
        f16x8 bha = *(const f16x8*)(w0 + ta * 512);
        f16x8 bhb = *(const f16x8*)(w0 + tb * 512);
        f16x8 bla = *(const f16x8*)(w0 + 4096 + ta * 512);
        f16x8 blb = *(const f16x8*)(w0 + 4096 + tb * 512);

        // chunk body: convert current A, 12 MFMAs. Chain order per accumulator
        // identical to R6 (a0: hi*hi; a1: hi*lo, lo*hi).
        auto body = [&]() {
            f16x8 ah0, al0, ah1, al1;
            split8(x0a, x0b, ah0, al0);
            split8(x1a, x1b, ah1, al1);
            a0[0][0] = __builtin_amdgcn_mfma_f32_16x16x32_f16(ah0, bha, a0[0][0], 0, 0, 0);
            a0[0][1] = __builtin_amdgcn_mfma_f32_16x16x32_f16(ah0, bhb, a0[0][1], 0, 0, 0);
            a1[0][0] = __builtin_amdgcn_mfma_f32_16x16x32_f16(ah0, bla, a1[0][0], 0, 0, 0);
            a1[0][1] = __builtin_amdgcn_mfma_f32_16x16x32_f16(ah0, blb, a1[0][1], 0, 0, 0);
            a1[0][0] = __builtin_amdgcn_mfma_f32_16x16x32_f16(al0, bha, a1[0][0], 0, 0, 0);
            a1[0][1] = __builtin_amdgcn_mfma_f32_16x16x32_f16(al0, bhb, a1[0][1], 0, 0, 0);
            a0[1][0] = __builtin_amdgcn_mfma_f32_16x16x32_f16(ah1, bha, a0[1][0], 0, 0, 0);
            a0[1][1] = __builtin_amdgcn_mfma_f32_16x16x32_f16(ah1, bhb, a0[1][1], 0, 0, 0);
            a1[1][0] = __builtin_amdgcn_mfma_f32_16x16x32_f16(ah1, bla, a1[1][0], 0, 0, 0);
            a1[1][1] = __builtin_amdgcn_mfma_f32_16x16x32_f16(ah1, blb, a1[1][1], 0, 0, 0);
            a1[1][0] = __builtin_amdgcn_mfma_f32_16x16x32_f16(al1, bha, a1[1][0], 0, 0, 0);
            a1[1][1] = __builtin_amdgcn_mfma_f32_16x16x32_f16(al1, bhb, a1[1][1], 0, 0, 0);
        };

        for (int c = cbeg; c < cbeg + CPS - 1; ++c) {
            // issue next chunk's loads; they fly across this chunk's MFMAs
            const float4 y0a = *(const float4*)(xr0 + (size_t)(c + 1) * KC);
            const float4 y0b = *(const float4*)(xr0 + (size_t)(c + 1) * KC + 4);
            const float4 y1a = *(const float4*)(xr1 + (size_t)(c + 1) * KC);
            const float4 y1b = *(const float4*)(xr1 + (size_t)(c + 1) * KC + 4);
            const _Float16* wn = wl + (size_t)(c + 1) * 8192;
            const f16x8 cha = *(const f16x8*)(wn + ta * 512);
            const f16x8 chb = *(const f16x8*)(wn + tb * 512);
            const f16x8 cla = *(const f16x8*)(wn + 4096 + ta * 512);
            const f16x8 clb = *(const f16x8*)(wn + 4096 + tb * 512);
            body();
            x0a = y0a; x0b = y0b; x1a = y1a; x1b = y1b;
            bha = cha; bhb = chb; bla = cla; blb = clb;
        }
        body();   // peeled last chunk (no prefetch -> no OOB reads)
    };

    zero_acc();
    run_seg(0);
    #pragma unroll
    for (int m = 0; m < 2; ++m)
        #pragma unroll
        for (int i = 0; i < 2; ++i)
            zk0[m][i] = a0[m][i] + a1[m][i] * 4.8828125e-4f;   // R6 zpart ks=0 fold

    zero_acc();
    run_seg(CPS);

    // segment-1 fold + f64 combine (identical to R6 epi), stage to LDS.
    // C/D layout: col = lane&15 (n within tile), row = q*4 + r.
    #pragma unroll
    for (int m = 0; m < 2; ++m)
        #pragma unroll
        for (int i = 0; i < 2; ++i) {
            const int n = (ta + i) * 16 + col;
            #pragma unroll
            for (int r = 0; r < 4; ++r) {
                const float zk1 = a0[m][i][r] + a1[m][i][r] * 4.8828125e-4f;
                const float comb = (float)((double)zk0[m][i][r] + (double)zk1);
                zs[(m * 16 + q * 4 + r) * ZROW + n] = comb;
            }
        }
    __syncthreads();

    // ---- epilogue: softplus, softmax/top8/masked softmax (verbatim R6 epi).
    const float b1v = b1[lane];
    const float b2v = b2[lane];
    for (int tt = 0; tt < 8; ++tt) {
        const int lt = wu * 8 + tt;
        const long tok = tok0 + lt;
        const float z1 = zs[lt * ZROW + lane] + b1v;
        const float z2 = zs[lt * ZROW + 64 + lane] + b2v;
        const float sc = (float)log1p(exp((double)z2));   // f64 softplus
        const float nz = noise[tok * NE + lane];
        const float mixed = z1 + nz * sc;

        // full softmax across the wave (lane = expert)
        float vmax = mixed;
        for (int off = 32; off; off >>= 1) vmax = fmaxf(vmax, __shfl_xor(vmax, off));
        const float e = expf(mixed - vmax);
        float denom = e;
        for (int off = 32; off; off >>= 1) denom += __shfl_xor(denom, off);
        const float fullv = e / denom;

        // top-8 iterative butterfly argmax, tie-break lowest index
        float cur = mixed;
        int   sel = 0;
        float myidxf = 0.0f;
        #pragma unroll
        for (int r = 0; r < NK; ++r) {
            float bv = cur; int bi = lane;
            for (int off = 32; off; off >>= 1) {
                const float ov = __shfl_xor(bv, off);
                const int   oi = __shfl_xor(bi, off);
                if (ov > bv || (ov == bv && oi < bi)) { bv = ov; bi = oi; }
            }
            if (lane == r)  myidxf = (float)bi;
            if (lane == bi) { sel = 1; cur = -INFINITY; }
        }

        const float es = sel ? e : 0.0f;
        float dsum = es;
        for (int off = 32; off; off >>= 1) dsum += __shfl_xor(dsum, off);
        const float sparsev = sel ? (e / dsum) : 0.0f;

        out_full[tok * NE + lane]   = fullv;
        out_sparse[tok * NE + lane] = sparsev;
        if (lane < NK) out_idx[tok * NK + lane] = myidxf;
    }
}

extern "C" void kernel_launch(void* const* d_in, const int* in_sizes, int n_in,
                              void* d_out, int out_size, void* d_ws, size_t ws_size,
                              hipStream_t stream) {
    const float* x     = (const float*)d_in[0];
    const float* noise = (const float*)d_in[1];
    const float* W1    = (const float*)d_in[2];
    const float* b1    = (const float*)d_in[3];
    const float* W2    = (const float*)d_in[4];
    const float* b2    = (const float*)d_in[5];

    float* out_sparse = (float*)d_out;                      // [16384*64]
    float* out_idx    = out_sparse + (size_t)NTOK * NE;     // [16384*8]
    float* out_full   = out_idx + (size_t)NTOK * NK;        // [16384*64]

    _Float16* wt3 = (_Float16*)d_ws;                        // 1 MB fragment-order W

    prep_w<<<128, 256, 0, stream>>>(W1, W2, wt3);
    router_fused<<<NTOK / MTOK, 256, 0, stream>>>(x, wt3, noise, b1, b2,
                                                  out_sparse, out_idx, out_full);
}

// Round 2
// 262.455 us; speedup vs baseline: 1.0891x; 1.0891x over previous
//
#include <hip/hip_runtime.h>
#include <math.h>

// R8: fused NoisyTopkRouter, LDS-staged 4-chunk stages, 1 barrier/stage.
// R7 evidence: barrier-free direct-from-global A-frags collapsed to 5600
// cyc/chunk (MfmaUtil 6.9%, VALUBusy 24.7%) -- per-chunk exposed latency:
// 2 waves/SIMD, compiler-sunk 1-deep prefetch, 16-way-scattered A loads.
// R8 structure (catalog T3-minimum + T14 + T2):
//  - x staged in LDS, 4 MFMA-chunks (512 B/token) per stage, 16 stages.
//  - ONE barrier per stage: double-buffered LDS, stage s = [read buf(s&1),
//    write buf(s+1&1)], barrier. Write->read and read->write pairs are each
//    separated by exactly one barrier.
//  - Global x loads (4x float4/thread, fully coalesced) issued BEFORE the
//    MFMA cluster; vmcnt wait lands after ~300 cy of MFMA+ds_read (T14).
//  - T2 XOR swizzle on 16-B slots of the 128-B token row:
//    slot ^= (tok&7) ^ ((chunk&1)<<2) -> ds_read_b128 A-frags 2-way (free).
//  - B-frags straight from fragment-ordered wt3 (L2-resident, R7-verified).
//  - Fused epilogue (R7's, verified): zs tile in LDS (aliases stage bufs),
//    verbatim softmax/top8/masked-softmax.
// Numerics bit-identical to R6/R7: same per-accumulator MFMA chain order,
// same chunk order, seg folds after chunks 31/63, f64 combine, f64 softplus.
// d_ws: 1 MB (wt3 only).

typedef _Float16 f16x8 __attribute__((ext_vector_type(8)));
typedef _Float16 f16x4 __attribute__((ext_vector_type(4)));
typedef float f32x4 __attribute__((ext_vector_type(4)));

constexpr int ND = 2048, NE = 64, NK = 8, NTOK = 16384;
constexpr int KC   = 32;            // k per chunk (one MFMA K)
constexpr int NCHT = ND / KC;       // 64 chunks
constexpr int CPSG = 4;             // chunks per stage
constexpr int NSTG = NCHT / CPSG;   // 16 stages
constexpr int HSTG = NSTG / 2;      // numeric K-split boundary (after stage 7)
constexpr int MTOK = 32;            // tokens per block
constexpr int ZROW = 132;           // padded fp32 LDS row for epilogue
constexpr int STG_F16 = CPSG * MTOK * 64;   // 8192 f16 = 16 KB per buffer

// ---- prep: W1|W2 -> f16 hi / lo*2^11 planes in MFMA B-fragment order (unchanged).
__global__ void prep_w(const float* __restrict__ W1, const float* __restrict__ W2,
                       _Float16* __restrict__ wt3) {
    const int g    = blockIdx.x * 256 + threadIdx.x;   // 0..32767
    const int cg   = g >> 9;
    const int rem  = g & 511;
    const int t    = rem >> 6;
    const int lane = rem & 63;
    const int col  = lane & 15, q = lane >> 4;
    const int n    = t * 16 + col;
    const float* W = (t < 4) ? W1 : W2;
    const int cn   = n & 63;
    _Float16 h[8], l[8];
    #pragma unroll
    for (int j = 0; j < 8; ++j) {
        const float v = W[(size_t)(cg * 32 + q * 8 + j) * 64 + cn];
        const _Float16 hh = (_Float16)v;
        h[j] = hh;
        l[j] = (_Float16)((v - (float)hh) * 2048.0f);
    }
    *(f16x8*)&wt3[((size_t)(cg * 2 + 0) * 8 + t) * 512 + lane * 8] = *(f16x8*)h;
    *(f16x8*)&wt3[((size_t)(cg * 2 + 1) * 8 + t) * 512 + lane * 8] = *(f16x8*)l;
}

__device__ __forceinline__ void split4(const float4 v, f16x4& hh, f16x4& ll) {
    const _Float16 h0 = (_Float16)v.x, h1 = (_Float16)v.y,
                   h2 = (_Float16)v.z, h3 = (_Float16)v.w;
    hh = (f16x4){h0, h1, h2, h3};
    ll = (f16x4){(_Float16)((v.x - (float)h0) * 2048.0f),
                 (_Float16)((v.y - (float)h1) * 2048.0f),
                 (_Float16)((v.z - (float)h2) * 2048.0f),
                 (_Float16)((v.w - (float)h3) * 2048.0f)};
}

__global__ __launch_bounds__(256, 2)
void router_fused(const float* __restrict__ x, const _Float16* __restrict__ wt3,
                  const float* __restrict__ noise,
                  const float* __restrict__ b1, const float* __restrict__ b2,
                  float* __restrict__ out_sparse, float* __restrict__ out_idx,
                  float* __restrict__ out_full) {
    __shared__ __align__(16) _Float16 stage[2][STG_F16];   // 32 KB total
    const int tid  = threadIdx.x;
    const int lane = tid & 63;
    const int wu   = __builtin_amdgcn_readfirstlane(tid >> 6);
    const int col  = lane & 15, q = lane >> 4;
    const long tok0 = (long)blockIdx.x * MTOK;
    const int ta = 2 * wu, tb = 2 * wu + 1;   // this wave's N-tiles

    // staging map: 8 threads/token; thread's j-th float4 = chunk j, k = lsub*4.
    // LDS row (128 B) = [hi: slots 0-3][lo: slots 4-7] of 16 B; swizzled slot =
    // raw ^ (tok&7) ^ ((chunk&1)<<2). Thread writes f16x4 halves (wh selects 8B).
    const int stok = tid >> 3, lsub = tid & 7;
    const float* xs = x + (tok0 + stok) * (size_t)ND + lsub * 4;
    const int wS = lsub >> 1, wh = lsub & 1;

    const _Float16* wla = wt3 + (size_t)ta * 512 + (size_t)lane * 8;
    const _Float16* wlb = wt3 + (size_t)tb * 512 + (size_t)lane * 8;

    f32x4 a0[2][2], a1[2][2], zk0[2][2];
    #pragma unroll
    for (int m = 0; m < 2; ++m)
        #pragma unroll
        for (int i = 0; i < 2; ++i)
            #pragma unroll
            for (int r = 0; r < 4; ++r) { a0[m][i][r] = 0.f; a1[m][i][r] = 0.f; }

    // prologue: stage 0
    {
        float4 cur[4];
        #pragma unroll
        for (int j = 0; j < 4; ++j) cur[j] = *(const float4*)(xs + (size_t)j * KC);
        #pragma unroll
        for (int j = 0; j < 4; ++j) {
            f16x4 hv, lv; split4(cur[j], hv, lv);
            const int idx = ((j * MTOK + stok) << 6)
                          + (((wS ^ (stok & 7) ^ ((j & 1) << 2)) << 3) + (wh << 2));
            *(f16x4*)&stage[0][idx]      = hv;
            *(f16x4*)&stage[0][idx ^ 32] = lv;
        }
    }
    __syncthreads();

    for (int s = 0; s < NSTG; ++s) {
        const _Float16* rb = stage[s & 1];
        float4 nxt[4];
        if (s + 1 < NSTG) {
            #pragma unroll
            for (int j = 0; j < 4; ++j)
                nxt[j] = *(const float4*)(xs + (size_t)(s + 1) * 128 + (size_t)j * KC);
        }
        #pragma unroll
        for (int cc = 0; cc < CPSG; ++cc) {
            const size_t cb = (size_t)(s * CPSG + cc) * 8192;
            const f16x8 bha = *(const f16x8*)(wla + cb);
            const f16x8 bhb = *(const f16x8*)(wlb + cb);
            const f16x8 blx = *(const f16x8*)(wla + cb + 4096);
            const f16x8 bly = *(const f16x8*)(wlb + cb + 4096);
            const int swz = (cc & 1) << 2;
            #pragma unroll
            for (int mt = 0; mt < 2; ++mt) {
                const int ridx = ((cc * MTOK + mt * 16 + col) << 6)
                               + ((q ^ (col & 7) ^ swz) << 3);
                const f16x8 ah = *(const f16x8*)&rb[ridx];
                const f16x8 al = *(const f16x8*)&rb[ridx ^ 32];
                // per-accumulator chain order identical to R6/R7
                a0[mt][0] = __builtin_amdgcn_mfma_f32_16x16x32_f16(ah, bha, a0[mt][0], 0, 0, 0);
                a0[mt][1] = __builtin_amdgcn_mfma_f32_16x16x32_f16(ah, bhb, a0[mt][1], 0, 0, 0);
                a1[mt][0] = __builtin_amdgcn_mfma_f32_16x16x32_f16(ah, blx, a1[mt][0], 0, 0, 0);
                a1[mt][1] = __builtin_amdgcn_mfma_f32_16x16x32_f16(ah, bly, a1[mt][1], 0, 0, 0);
                a1[mt][0] = __builtin_amdgcn_mfma_f32_16x16x32_f16(al, bha, a1[mt][0], 0, 0, 0);
                a1[mt][1] = __builtin_amdgcn_mfma_f32_16x16x32_f16(al, bhb, a1[mt][1], 0, 0, 0);
            }
        }
        if (s == HSTG - 1) {   // chunks 0..31 done: fold seg-0 partial, reset acc
            #pragma unroll
            for (int m = 0; m < 2; ++m)
                #pragma unroll
                for (int i = 0; i < 2; ++i) {
                    zk0[m][i] = a0[m][i] + a1[m][i] * 4.8828125e-4f;
                    #pragma unroll
                    for (int r = 0; r < 4; ++r) { a0[m][i][r] = 0.f; a1[m][i][r] = 0.f; }
                }
        }
        if (s + 1 < NSTG) {
            _Float16* wb = stage[(s + 1) & 1];
            #pragma unroll
            for (int j = 0; j < 4; ++j) {
                f16x4 hv, lv; split4(nxt[j], hv, lv);
                const int idx = ((j * MTOK + stok) << 6)
                              + (((wS ^ (stok & 7) ^ ((j & 1) << 2)) << 3) + (wh << 2));
                *(f16x4*)&wb[idx]      = hv;
                *(f16x4*)&wb[idx ^ 32] = lv;
            }
        }
        __syncthreads();
    }

    // seg-1 fold + f64 combine, stage z-tile to LDS (aliases stage bufs; all
    // frag reads completed at the final stage barrier above).
    float* zs = (float*)&stage[0][0];   // needs 32*132*4 = 16.9 KB <= 32 KB
    #pragma unroll
    for (int m = 0; m < 2; ++m)
        #pragma unroll
        for (int i = 0; i < 2; ++i) {
            const int n = (ta + i) * 16 + col;
            #pragma unroll
            for (int r = 0; r < 4; ++r) {
                const float zk1 = a0[m][i][r] + a1[m][i][r] * 4.8828125e-4f;
                const float comb = (float)((double)zk0[m][i][r] + (double)zk1);
                zs[(m * 16 + q * 4 + r) * ZROW + n] = comb;
            }
        }
    __syncthreads();

    // ---- epilogue: softplus, softmax/top8/masked softmax (verbatim).
    const float b1v = b1[lane];
    const float b2v = b2[lane];
    for (int tt = 0; tt < 8; ++tt) {
        const int lt = wu * 8 + tt;
        const long tok = tok0 + lt;
        const float z1 = zs[lt * ZROW + lane] + b1v;
        const float z2 = zs[lt * ZROW + 64 + lane] + b2v;
        const float sc = (float)log1p(exp((double)z2));   // f64 softplus
        const float nz = noise[tok * NE + lane];
        const float mixed = z1 + nz * sc;

        float vmax = mixed;
        for (int off = 32; off; off >>= 1) vmax = fmaxf(vmax, __shfl_xor(vmax, off));
        const float e = expf(mixed - vmax);
        float denom = e;
        for (int off = 32; off; off >>= 1) denom += __shfl_xor(denom, off);
        const float fullv = e / denom;

        float cur = mixed;
        int   sel = 0;
        float myidxf = 0.0f;
        #pragma unroll
        for (int r = 0; r < NK; ++r) {
            float bv = cur; int bi = lane;
            for (int off = 32; off; off >>= 1) {
                const float ov = __shfl_xor(bv, off);
                const int   oi = __shfl_xor(bi, off);
                if (ov > bv || (ov == bv && oi < bi)) { bv = ov; bi = oi; }
            }
            if (lane == r)  myidxf = (float)bi;
            if (lane == bi) { sel = 1; cur = -INFINITY; }
        }

        const float es = sel ? e : 0.0f;
        float dsum = es;
        for (int off = 32; off; off >>= 1) dsum += __shfl_xor(dsum, off);
        const float sparsev = sel ? (e / dsum) : 0.0f;

        out_full[tok * NE + lane]   = fullv;
        out_sparse[tok * NE + lane] = sparsev;
        if (lane < NK) out_idx[tok * NK + lane] = myidxf;
    }
}

extern "C" void kernel_launch(void* const* d_in, const int* in_sizes, int n_in,
                              void* d_out, int out_size, void* d_ws, size_t ws_size,
                              hipStream_t stream) {
    const float* x     = (const float*)d_in[0];
    const float* noise = (const float*)d_in[1];
    const float* W1    = (const float*)d_in[2];
    const float* b1    = (const float*)d_in[3];
    const float* W2    = (const float*)d_in[4];
    const float* b2    = (const float*)d_in[5];

    float* out_sparse = (float*)d_out;                      // [16384*64]
    float* out_idx    = out_sparse + (size_t)NTOK * NE;     // [16384*8]
    float* out_full   = out_idx + (size_t)NTOK * NK;        // [16384*64]

    _Float16* wt3 = (_Float16*)d_ws;                        // 1 MB fragment-order W

    prep_w<<<128, 256, 0, stream>>>(W1, W2, wt3);
    router_fused<<<NTOK / MTOK, 256, 0, stream>>>(x, wt3, noise, b1, b2,
                                                  out_sparse, out_idx, out_full);
}

// Round 3
// 256.773 us; speedup vs baseline: 1.1132x; 1.0221x over previous
//
#include <hip/hip_runtime.h>
#include <math.h>

// R9: R8 with the load schedule fixed (vmcnt-interleave + register pipelining).
// R8 evidence: 118us, MfmaUtil 8.3%, VALUBusy 19%, VGPR=52 (< the 64 regs of
// accumulators alone -> nothing pipelined; B frags loaded just-in-time, one L2
// round trip per chunk). Worse: x prefetch issued BEFORE per-chunk B loads, and
// vmcnt completes in issue order -> every chunk's B wait also waited for the
// next stage's x HBM loads. Stage was a serial chain of ~5 memory round trips.
// R9 schedule per stage (numerics/layout byte-identical to R8):
//   1) issue ALL 16 B-frag loads (held in B[4][4] regs -> real VGPR allocation)
//   2) issue 4 x loads for stage s+2 (NEWEST -> B waits exclude x; the x data
//      written this stage was issued two stages ago -> its drain is free)
//   3) 4 chunks of ds_read A + 12 MFMA (compiler inserts counted vmcnt per chunk)
//   4) seg fold at stage 7 (chunks 0..31), as before
//   5) split4 + swizzled LDS write of stage s+1 x; ONE barrier
// Stage loop unrolled x2 so buffers and xa/xb roles are compile-time (no copies).
// d_ws: 1 MB (wt3 only).

typedef _Float16 f16x8 __attribute__((ext_vector_type(8)));
typedef _Float16 f16x4 __attribute__((ext_vector_type(4)));
typedef float f32x4 __attribute__((ext_vector_type(4)));

constexpr int ND = 2048, NE = 64, NK = 8, NTOK = 16384;
constexpr int KC   = 32;            // k per chunk (one MFMA K)
constexpr int NCHT = ND / KC;       // 64 chunks
constexpr int CPSG = 4;             // chunks per stage
constexpr int NSTG = NCHT / CPSG;   // 16 stages
constexpr int HSTG = NSTG / 2;      // numeric K-split boundary (after stage 7)
constexpr int MTOK = 32;            // tokens per block
constexpr int ZROW = 132;           // padded fp32 LDS row for epilogue
constexpr int STG_F16 = CPSG * MTOK * 64;   // 8192 f16 = 16 KB per buffer

// ---- prep: W1|W2 -> f16 hi / lo*2^11 planes in MFMA B-fragment order (unchanged).
__global__ void prep_w(const float* __restrict__ W1, const float* __restrict__ W2,
                       _Float16* __restrict__ wt3) {
    const int g    = blockIdx.x * 256 + threadIdx.x;   // 0..32767
    const int cg   = g >> 9;
    const int rem  = g & 511;
    const int t    = rem >> 6;
    const int lane = rem & 63;
    const int col  = lane & 15, q = lane >> 4;
    const int n    = t * 16 + col;
    const float* W = (t < 4) ? W1 : W2;
    const int cn   = n & 63;
    _Float16 h[8], l[8];
    #pragma unroll
    for (int j = 0; j < 8; ++j) {
        const float v = W[(size_t)(cg * 32 + q * 8 + j) * 64 + cn];
        const _Float16 hh = (_Float16)v;
        h[j] = hh;
        l[j] = (_Float16)((v - (float)hh) * 2048.0f);
    }
    *(f16x8*)&wt3[((size_t)(cg * 2 + 0) * 8 + t) * 512 + lane * 8] = *(f16x8*)h;
    *(f16x8*)&wt3[((size_t)(cg * 2 + 1) * 8 + t) * 512 + lane * 8] = *(f16x8*)l;
}

__device__ __forceinline__ void split4(const float4 v, f16x4& hh, f16x4& ll) {
    const _Float16 h0 = (_Float16)v.x, h1 = (_Float16)v.y,
                   h2 = (_Float16)v.z, h3 = (_Float16)v.w;
    hh = (f16x4){h0, h1, h2, h3};
    ll = (f16x4){(_Float16)((v.x - (float)h0) * 2048.0f),
                 (_Float16)((v.y - (float)h1) * 2048.0f),
                 (_Float16)((v.z - (float)h2) * 2048.0f),
                 (_Float16)((v.w - (float)h3) * 2048.0f)};
}

__global__ __launch_bounds__(256, 2)
void router_fused(const float* __restrict__ x, const _Float16* __restrict__ wt3,
                  const float* __restrict__ noise,
                  const float* __restrict__ b1, const float* __restrict__ b2,
                  float* __restrict__ out_sparse, float* __restrict__ out_idx,
                  float* __restrict__ out_full) {
    __shared__ __align__(16) _Float16 stage[2][STG_F16];   // 32 KB total
    const int tid  = threadIdx.x;
    const int lane = tid & 63;
    const int wu   = __builtin_amdgcn_readfirstlane(tid >> 6);
    const int col  = lane & 15, q = lane >> 4;
    const long tok0 = (long)blockIdx.x * MTOK;
    const int ta = 2 * wu, tb = 2 * wu + 1;   // this wave's N-tiles

    // staging map: 8 threads/token; thread's j-th float4 = chunk j, k = lsub*4.
    const int stok = tid >> 3, lsub = tid & 7;
    const float* xs = x + (tok0 + stok) * (size_t)ND + lsub * 4;
    const int wS = lsub >> 1, wh = lsub & 1;

    const _Float16* wla = wt3 + (size_t)ta * 512 + (size_t)lane * 8;
    const _Float16* wlb = wt3 + (size_t)tb * 512 + (size_t)lane * 8;

    f32x4 a0[2][2], a1[2][2], zk0[2][2];
    #pragma unroll
    for (int m = 0; m < 2; ++m)
        #pragma unroll
        for (int i = 0; i < 2; ++i)
            #pragma unroll
            for (int r = 0; r < 4; ++r) { a0[m][i][r] = 0.f; a1[m][i][r] = 0.f; }

    float4 xa[4], xb[4];   // x reg double-buffer: data for stages s+1 / s+2

    // deposit: split one stage's 4 float4s into the swizzled hi/lo LDS layout
    auto deposit = [&](_Float16* wb, const float4 (&xr)[4]) {
        #pragma unroll
        for (int j = 0; j < 4; ++j) {
            f16x4 hv, lv; split4(xr[j], hv, lv);
            const int idx = ((j * MTOK + stok) << 6)
                          + (((wS ^ (stok & 7) ^ ((j & 1) << 2)) << 3) + (wh << 2));
            *(f16x4*)&wb[idx]      = hv;
            *(f16x4*)&wb[idx ^ 32] = lv;
        }
    };

    // one stage: read rb, issue B first then x(s+2) into xl, MFMA, write xw->wb.
    auto do_stage = [&](const int s, const _Float16* rb, _Float16* wb,
                        const float4 (&xw)[4], float4 (&xl)[4]) {
        // 1) all 16 B-frag loads for this stage, in registers
        f16x8 B[CPSG][4];
        #pragma unroll
        for (int cc = 0; cc < CPSG; ++cc) {
            const size_t cb = (size_t)(s * CPSG + cc) * 8192;
            B[cc][0] = *(const f16x8*)(wla + cb);
            B[cc][1] = *(const f16x8*)(wlb + cb);
            B[cc][2] = *(const f16x8*)(wla + cb + 4096);
            B[cc][3] = *(const f16x8*)(wlb + cb + 4096);
        }
        // 2) x loads for stage s+2 (newest -> B waits exclude them)
        if (s + 2 < NSTG) {
            #pragma unroll
            for (int j = 0; j < 4; ++j)
                xl[j] = *(const float4*)(xs + (size_t)(s + 2) * 128 + (size_t)j * KC);
        }
        // 3) chunks
        #pragma unroll
        for (int cc = 0; cc < CPSG; ++cc) {
            const int swz = (cc & 1) << 2;
            #pragma unroll
            for (int mt = 0; mt < 2; ++mt) {
                const int ridx = ((cc * MTOK + mt * 16 + col) << 6)
                               + ((q ^ (col & 7) ^ swz) << 3);
                const f16x8 ah = *(const f16x8*)&rb[ridx];
                const f16x8 al = *(const f16x8*)&rb[ridx ^ 32];
                // per-accumulator chain order identical to R6/R7/R8
                a0[mt][0] = __builtin_amdgcn_mfma_f32_16x16x32_f16(ah, B[cc][0], a0[mt][0], 0, 0, 0);
                a0[mt][1] = __builtin_amdgcn_mfma_f32_16x16x32_f16(ah, B[cc][1], a0[mt][1], 0, 0, 0);
                a1[mt][0] = __builtin_amdgcn_mfma_f32_16x16x32_f16(ah, B[cc][2], a1[mt][0], 0, 0, 0);
                a1[mt][1] = __builtin_amdgcn_mfma_f32_16x16x32_f16(ah, B[cc][3], a1[mt][1], 0, 0, 0);
                a1[mt][0] = __builtin_amdgcn_mfma_f32_16x16x32_f16(al, B[cc][0], a1[mt][0], 0, 0, 0);
                a1[mt][1] = __builtin_amdgcn_mfma_f32_16x16x32_f16(al, B[cc][1], a1[mt][1], 0, 0, 0);
            }
        }
        // 4) numeric K-split fold after chunks 0..31
        if (s == HSTG - 1) {
            #pragma unroll
            for (int m = 0; m < 2; ++m)
                #pragma unroll
                for (int i = 0; i < 2; ++i) {
                    zk0[m][i] = a0[m][i] + a1[m][i] * 4.8828125e-4f;
                    #pragma unroll
                    for (int r = 0; r < 4; ++r) { a0[m][i][r] = 0.f; a1[m][i][r] = 0.f; }
                }
        }
        // 5) write stage s+1's x (issued two stages ago; drain is free)
        if (s + 1 < NSTG) deposit(wb, xw);
        __syncthreads();
    };

    // prologue: stage-0 deposit, then issue stage-1 x into xa
    {
        float4 x0[4];
        #pragma unroll
        for (int j = 0; j < 4; ++j) x0[j] = *(const float4*)(xs + (size_t)j * KC);
        deposit(stage[0], x0);
        #pragma unroll
        for (int j = 0; j < 4; ++j)
            xa[j] = *(const float4*)(xs + (size_t)128 + (size_t)j * KC);
    }
    __syncthreads();

    // main loop, unrolled x2: buffers and xa/xb roles compile-time
    for (int sp = 0; sp < NSTG; sp += 2) {
        do_stage(sp,     stage[0], stage[1], xa, xb);
        do_stage(sp + 1, stage[1], stage[0], xb, xa);
    }

    // seg-1 fold + f64 combine, stage z-tile to LDS (aliases stage bufs).
    float* zs = (float*)&stage[0][0];   // 32*132*4 = 16.9 KB <= 32 KB
    #pragma unroll
    for (int m = 0; m < 2; ++m)
        #pragma unroll
        for (int i = 0; i < 2; ++i) {
            const int n = (ta + i) * 16 + col;
            #pragma unroll
            for (int r = 0; r < 4; ++r) {
                const float zk1 = a0[m][i][r] + a1[m][i][r] * 4.8828125e-4f;
                const float comb = (float)((double)zk0[m][i][r] + (double)zk1);
                zs[(m * 16 + q * 4 + r) * ZROW + n] = comb;
            }
        }
    __syncthreads();

    // ---- epilogue: softplus, softmax/top8/masked softmax (verbatim).
    const float b1v = b1[lane];
    const float b2v = b2[lane];
    for (int tt = 0; tt < 8; ++tt) {
        const int lt = wu * 8 + tt;
        const long tok = tok0 + lt;
        const float z1 = zs[lt * ZROW + lane] + b1v;
        const float z2 = zs[lt * ZROW + 64 + lane] + b2v;
        const float sc = (float)log1p(exp((double)z2));   // f64 softplus
        const float nz = noise[tok * NE + lane];
        const float mixed = z1 + nz * sc;

        float vmax = mixed;
        for (int off = 32; off; off >>= 1) vmax = fmaxf(vmax, __shfl_xor(vmax, off));
        const float e = expf(mixed - vmax);
        float denom = e;
        for (int off = 32; off; off >>= 1) denom += __shfl_xor(denom, off);
        const float fullv = e / denom;

        float cur = mixed;
        int   sel = 0;
        float myidxf = 0.0f;
        #pragma unroll
        for (int r = 0; r < NK; ++r) {
            float bv = cur; int bi = lane;
            for (int off = 32; off; off >>= 1) {
                const float ov = __shfl_xor(bv, off);
                const int   oi = __shfl_xor(bi, off);
                if (ov > bv || (ov == bv && oi < bi)) { bv = ov; bi = oi; }
            }
            if (lane == r)  myidxf = (float)bi;
            if (lane == bi) { sel = 1; cur = -INFINITY; }
        }

        const float es = sel ? e : 0.0f;
        float dsum = es;
        for (int off = 32; off; off >>= 1) dsum += __shfl_xor(dsum, off);
        const float sparsev = sel ? (e / dsum) : 0.0f;

        out_full[tok * NE + lane]   = fullv;
        out_sparse[tok * NE + lane] = sparsev;
        if (lane < NK) out_idx[tok * NK + lane] = myidxf;
    }
}

extern "C" void kernel_launch(void* const* d_in, const int* in_sizes, int n_in,
                              void* d_out, int out_size, void* d_ws, size_t ws_size,
                              hipStream_t stream) {
    const float* x     = (const float*)d_in[0];
    const float* noise = (const float*)d_in[1];
    const float* W1    = (const float*)d_in[2];
    const float* b1    = (const float*)d_in[3];
    const float* W2    = (const float*)d_in[4];
    const float* b2    = (const float*)d_in[5];

    float* out_sparse = (float*)d_out;                      // [16384*64]
    float* out_idx    = out_sparse + (size_t)NTOK * NE;     // [16384*8]
    float* out_full   = out_idx + (size_t)NTOK * NK;        // [16384*64]

    _Float16* wt3 = (_Float16*)d_ws;                        // 1 MB fragment-order W

    prep_w<<<128, 256, 0, stream>>>(W1, W2, wt3);
    router_fused<<<NTOK / MTOK, 256, 0, stream>>>(x, wt3, noise, b1, b2,
                                                  out_sparse, out_idx, out_full);
}

// Round 4
// 255.867 us; speedup vs baseline: 1.1171x; 1.0035x over previous
//
#include <hip/hip_runtime.h>
#include <math.h>

// R10: R9 + non-draining barriers (the actual fix for the pipeline collapse).
// R9 evidence: 112us, MfmaUtil 8.9%, VGPR=104 (B regs allocated) -- pipelining
// was in place but __syncthreads() emits s_waitcnt vmcnt(0) before s_barrier,
// so every stage's x(s+2) HBM loads and B prefetches had to COMPLETE before any
// wave crossed the stage barrier: the 2-stage pipeline ran fully serialized.
// R10 changes (numerics/layout byte-identical to R8/R9):
//  - in-loop barrier = inline-asm "s_waitcnt lgkmcnt(0)" + raw s_barrier.
//    LDS producer->consumer ordering is preserved (lgkm drain + barrier);
//    vmcnt stays COUNTED (compiler's dependency waits), so global loads
//    remain in flight across barriers (catalog T3/T4 minimum form).
//  - B double-buffered in registers: B(s+1) issued during stage s, consumed
//    after the barrier -> chunk-0 L2 latency pre-hidden.
//  - x issued 2 stages ahead (newest in issue order -> B waits exclude x).
// d_ws: 1 MB (wt3 only).

typedef _Float16 f16x8 __attribute__((ext_vector_type(8)));
typedef _Float16 f16x4 __attribute__((ext_vector_type(4)));
typedef float f32x4 __attribute__((ext_vector_type(4)));

constexpr int ND = 2048, NE = 64, NK = 8, NTOK = 16384;
constexpr int KC   = 32;            // k per chunk (one MFMA K)
constexpr int NCHT = ND / KC;       // 64 chunks
constexpr int CPSG = 4;             // chunks per stage
constexpr int NSTG = NCHT / CPSG;   // 16 stages
constexpr int HSTG = NSTG / 2;      // numeric K-split boundary (after stage 7)
constexpr int MTOK = 32;            // tokens per block
constexpr int ZROW = 132;           // padded fp32 LDS row for epilogue
constexpr int STG_F16 = CPSG * MTOK * 64;   // 8192 f16 = 16 KB per buffer

// ---- prep: W1|W2 -> f16 hi / lo*2^11 planes in MFMA B-fragment order (unchanged).
__global__ void prep_w(const float* __restrict__ W1, const float* __restrict__ W2,
                       _Float16* __restrict__ wt3) {
    const int g    = blockIdx.x * 256 + threadIdx.x;   // 0..32767
    const int cg   = g >> 9;
    const int rem  = g & 511;
    const int t    = rem >> 6;
    const int lane = rem & 63;
    const int col  = lane & 15, q = lane >> 4;
    const int n    = t * 16 + col;
    const float* W = (t < 4) ? W1 : W2;
    const int cn   = n & 63;
    _Float16 h[8], l[8];
    #pragma unroll
    for (int j = 0; j < 8; ++j) {
        const float v = W[(size_t)(cg * 32 + q * 8 + j) * 64 + cn];
        const _Float16 hh = (_Float16)v;
        h[j] = hh;
        l[j] = (_Float16)((v - (float)hh) * 2048.0f);
    }
    *(f16x8*)&wt3[((size_t)(cg * 2 + 0) * 8 + t) * 512 + lane * 8] = *(f16x8*)h;
    *(f16x8*)&wt3[((size_t)(cg * 2 + 1) * 8 + t) * 512 + lane * 8] = *(f16x8*)l;
}

__device__ __forceinline__ void split4(const float4 v, f16x4& hh, f16x4& ll) {
    const _Float16 h0 = (_Float16)v.x, h1 = (_Float16)v.y,
                   h2 = (_Float16)v.z, h3 = (_Float16)v.w;
    hh = (f16x4){h0, h1, h2, h3};
    ll = (f16x4){(_Float16)((v.x - (float)h0) * 2048.0f),
                 (_Float16)((v.y - (float)h1) * 2048.0f),
                 (_Float16)((v.z - (float)h2) * 2048.0f),
                 (_Float16)((v.w - (float)h3) * 2048.0f)};
}

// non-draining block barrier: LDS ordering only; vmcnt stays counted.
__device__ __forceinline__ void block_sync_lds() {
    asm volatile("s_waitcnt lgkmcnt(0)" ::: "memory");
    __builtin_amdgcn_s_barrier();
}

__global__ __launch_bounds__(256, 2)
void router_fused(const float* __restrict__ x, const _Float16* __restrict__ wt3,
                  const float* __restrict__ noise,
                  const float* __restrict__ b1, const float* __restrict__ b2,
                  float* __restrict__ out_sparse, float* __restrict__ out_idx,
                  float* __restrict__ out_full) {
    __shared__ __align__(16) _Float16 stage[2][STG_F16];   // 32 KB total
    const int tid  = threadIdx.x;
    const int lane = tid & 63;
    const int wu   = __builtin_amdgcn_readfirstlane(tid >> 6);
    const int col  = lane & 15, q = lane >> 4;
    const long tok0 = (long)blockIdx.x * MTOK;
    const int ta = 2 * wu, tb = 2 * wu + 1;   // this wave's N-tiles

    // staging map: 8 threads/token; thread's j-th float4 = chunk j, k = lsub*4.
    const int stok = tid >> 3, lsub = tid & 7;
    const float* xs = x + (tok0 + stok) * (size_t)ND + lsub * 4;
    const int wS = lsub >> 1, wh = lsub & 1;

    const _Float16* wla = wt3 + (size_t)ta * 512 + (size_t)lane * 8;
    const _Float16* wlb = wt3 + (size_t)tb * 512 + (size_t)lane * 8;

    f32x4 a0[2][2], a1[2][2], zk0[2][2];
    #pragma unroll
    for (int m = 0; m < 2; ++m)
        #pragma unroll
        for (int i = 0; i < 2; ++i)
            #pragma unroll
            for (int r = 0; r < 4; ++r) { a0[m][i][r] = 0.f; a1[m][i][r] = 0.f; }

    f16x8 Ba[CPSG][4], Bb[CPSG][4];   // B-frag register double-buffer
    float4 xa[4], xb[4];              // x register double-buffer (2 stages ahead)

    auto loadB = [&](f16x8 (&B)[CPSG][4], const int s) {
        #pragma unroll
        for (int cc = 0; cc < CPSG; ++cc) {
            const size_t cb = (size_t)(s * CPSG + cc) * 8192;
            B[cc][0] = *(const f16x8*)(wla + cb);
            B[cc][1] = *(const f16x8*)(wlb + cb);
            B[cc][2] = *(const f16x8*)(wla + cb + 4096);
            B[cc][3] = *(const f16x8*)(wlb + cb + 4096);
        }
    };
    auto loadX = [&](float4 (&xr)[4], const int s) {
        #pragma unroll
        for (int j = 0; j < 4; ++j)
            xr[j] = *(const float4*)(xs + (size_t)s * 128 + (size_t)j * KC);
    };
    auto deposit = [&](_Float16* wb, const float4 (&xr)[4]) {
        #pragma unroll
        for (int j = 0; j < 4; ++j) {
            f16x4 hv, lv; split4(xr[j], hv, lv);
            const int idx = ((j * MTOK + stok) << 6)
                          + (((wS ^ (stok & 7) ^ ((j & 1) << 2)) << 3) + (wh << 2));
            *(f16x4*)&wb[idx]      = hv;
            *(f16x4*)&wb[idx ^ 32] = lv;
        }
    };

    // one stage: consume Bcur + rb; prefetch B(s+1)->Bnxt, x(s+2)->xl;
    // write xw (issued two stages ago) -> wb; non-draining barrier.
    auto do_stage = [&](const int s, const _Float16* rb, _Float16* wb,
                        const f16x8 (&Bcur)[CPSG][4], f16x8 (&Bnxt)[CPSG][4],
                        const float4 (&xw)[4], float4 (&xl)[4]) {
        if (s + 1 < NSTG) loadB(Bnxt, s + 1);
        if (s + 2 < NSTG) loadX(xl, s + 2);
        #pragma unroll
        for (int cc = 0; cc < CPSG; ++cc) {
            const int swz = (cc & 1) << 2;
            #pragma unroll
            for (int mt = 0; mt < 2; ++mt) {
                const int ridx = ((cc * MTOK + mt * 16 + col) << 6)
                               + ((q ^ (col & 7) ^ swz) << 3);
                const f16x8 ah = *(const f16x8*)&rb[ridx];
                const f16x8 al = *(const f16x8*)&rb[ridx ^ 32];
                // per-accumulator chain order identical to R6/R7/R8/R9
                a0[mt][0] = __builtin_amdgcn_mfma_f32_16x16x32_f16(ah, Bcur[cc][0], a0[mt][0], 0, 0, 0);
                a0[mt][1] = __builtin_amdgcn_mfma_f32_16x16x32_f16(ah, Bcur[cc][1], a0[mt][1], 0, 0, 0);
                a1[mt][0] = __builtin_amdgcn_mfma_f32_16x16x32_f16(ah, Bcur[cc][2], a1[mt][0], 0, 0, 0);
                a1[mt][1] = __builtin_amdgcn_mfma_f32_16x16x32_f16(ah, Bcur[cc][3], a1[mt][1], 0, 0, 0);
                a1[mt][0] = __builtin_amdgcn_mfma_f32_16x16x32_f16(al, Bcur[cc][0], a1[mt][0], 0, 0, 0);
                a1[mt][1] = __builtin_amdgcn_mfma_f32_16x16x32_f16(al, Bcur[cc][1], a1[mt][1], 0, 0, 0);
            }
        }
        if (s == HSTG - 1) {   // chunks 0..31 done: fold seg-0 partial, reset acc
            #pragma unroll
            for (int m = 0; m < 2; ++m)
                #pragma unroll
                for (int i = 0; i < 2; ++i) {
                    zk0[m][i] = a0[m][i] + a1[m][i] * 4.8828125e-4f;
                    #pragma unroll
                    for (int r = 0; r < 4; ++r) { a0[m][i][r] = 0.f; a1[m][i][r] = 0.f; }
                }
        }
        if (s + 1 < NSTG) deposit(wb, xw);
        block_sync_lds();
    };

    // prologue: stage-0 deposit; issue B(0) and x(1) (stay in flight past barrier)
    {
        float4 x0[4];
        loadX(x0, 0);
        deposit(stage[0], x0);
        loadB(Ba, 0);
        loadX(xa, 1);
    }
    block_sync_lds();

    // main loop, unrolled x2: buffers and register roles compile-time
    for (int sp = 0; sp < NSTG; sp += 2) {
        do_stage(sp,     stage[0], stage[1], Ba, Bb, xa, xb);
        do_stage(sp + 1, stage[1], stage[0], Bb, Ba, xb, xa);
    }

    // seg-1 fold + f64 combine, stage z-tile to LDS (aliases stage bufs; all
    // frag reads of stage[0] completed two barriers ago, stage[1] one ago).
    float* zs = (float*)&stage[0][0];   // 32*132*4 = 16.9 KB <= 32 KB
    #pragma unroll
    for (int m = 0; m < 2; ++m)
        #pragma unroll
        for (int i = 0; i < 2; ++i) {
            const int n = (ta + i) * 16 + col;
            #pragma unroll
            for (int r = 0; r < 4; ++r) {
                const float zk1 = a0[m][i][r] + a1[m][i][r] * 4.8828125e-4f;
                const float comb = (float)((double)zk0[m][i][r] + (double)zk1);
                zs[(m * 16 + q * 4 + r) * ZROW + n] = comb;
            }
        }
    __syncthreads();

    // ---- epilogue: softplus, softmax/top8/masked softmax (verbatim).
    const float b1v = b1[lane];
    const float b2v = b2[lane];
    for (int tt = 0; tt < 8; ++tt) {
        const int lt = wu * 8 + tt;
        const long tok = tok0 + lt;
        const float z1 = zs[lt * ZROW + lane] + b1v;
        const float z2 = zs[lt * ZROW + 64 + lane] + b2v;
        const float sc = (float)log1p(exp((double)z2));   // f64 softplus
        const float nz = noise[tok * NE + lane];
        const float mixed = z1 + nz * sc;

        float vmax = mixed;
        for (int off = 32; off; off >>= 1) vmax = fmaxf(vmax, __shfl_xor(vmax, off));
        const float e = expf(mixed - vmax);
        float denom = e;
        for (int off = 32; off; off >>= 1) denom += __shfl_xor(denom, off);
        const float fullv = e / denom;

        float cur = mixed;
        int   sel = 0;
        float myidxf = 0.0f;
        #pragma unroll
        for (int r = 0; r < NK; ++r) {
            float bv = cur; int bi = lane;
            for (int off = 32; off; off >>= 1) {
                const float ov = __shfl_xor(bv, off);
                const int   oi = __shfl_xor(bi, off);
                if (ov > bv || (ov == bv && oi < bi)) { bv = ov; bi = oi; }
            }
            if (lane == r)  myidxf = (float)bi;
            if (lane == bi) { sel = 1; cur = -INFINITY; }
        }

        const float es = sel ? e : 0.0f;
        float dsum = es;
        for (int off = 32; off; off >>= 1) dsum += __shfl_xor(dsum, off);
        const float sparsev = sel ? (e / dsum) : 0.0f;

        out_full[tok * NE + lane]   = fullv;
        out_sparse[tok * NE + lane] = sparsev;
        if (lane < NK) out_idx[tok * NK + lane] = myidxf;
    }
}

extern "C" void kernel_launch(void* const* d_in, const int* in_sizes, int n_in,
                              void* d_out, int out_size, void* d_ws, size_t ws_size,
                              hipStream_t stream) {
    const float* x     = (const float*)d_in[0];
    const float* noise = (const float*)d_in[1];
    const float* W1    = (const float*)d_in[2];
    const float* b1    = (const float*)d_in[3];
    const float* W2    = (const float*)d_in[4];
    const float* b2    = (const float*)d_in[5];

    float* out_sparse = (float*)d_out;                      // [16384*64]
    float* out_idx    = out_sparse + (size_t)NTOK * NE;     // [16384*8]
    float* out_full   = out_idx + (size_t)NTOK * NK;        // [16384*64]

    _Float16* wt3 = (_Float16*)d_ws;                        // 1 MB fragment-order W

    prep_w<<<128, 256, 0, stream>>>(W1, W2, wt3);
    router_fused<<<NTOK / MTOK, 256, 0, stream>>>(x, wt3, noise, b1, b2,
                                                  out_sparse, out_idx, out_full);
}

// Round 5
// 249.595 us; speedup vs baseline: 1.1452x; 1.0251x over previous
//
#include <hip/hip_runtime.h>
#include <math.h>

// R11: occupancy is the lever. R10 post-mortem: non-draining barriers + B dbuf
// changed nothing (112us, MfmaUtil 9%) -- at 8 waves/CU (grid 512, 2 blk/CU)
// no software pipeline can cover the latency chain, and VGPR=124 shows the
// allocator serialized the B dbuf anyway. Evidence: R6 ran 16 waves/CU through
// 128 draining barriers/block in 79us. TLP, not ILP.
// R11 = R10 skeleton with:
//  - MTOK 32->16: grid 1024 = 4 blocks/CU; per-wave work halved (1 M-tile,
//    acc 64->16 regs, deposit halved, LDS 32->16 KB/block).
//  - B single-buffered, issued at stage top (<=64 regs live); x 1 stage ahead
//    (8 regs). Structural max-live ~120 <= 128-VGPR cliff for 16 waves/CU;
//    __launch_bounds__(256,4) pins it.
//  - non-draining barriers kept (lgkmcnt(0) + s_barrier; vmcnt stays counted).
// Numerics byte-identical to R6..R10: same per-token MFMA chain order, chunk
// order, seg folds after chunks 31/63, f64 combine, f64 softplus epilogue.
// d_ws: 1 MB (wt3 only).

typedef _Float16 f16x8 __attribute__((ext_vector_type(8)));
typedef _Float16 f16x4 __attribute__((ext_vector_type(4)));
typedef float f32x4 __attribute__((ext_vector_type(4)));

constexpr int ND = 2048, NE = 64, NK = 8, NTOK = 16384;
constexpr int KC   = 32;            // k per chunk (one MFMA K)
constexpr int NCHT = ND / KC;       // 64 chunks
constexpr int CPSG = 4;             // chunks per stage
constexpr int NSTG = NCHT / CPSG;   // 16 stages
constexpr int HSTG = NSTG / 2;      // numeric K-split boundary (after stage 7)
constexpr int MTOK = 16;            // tokens per block (R11: halved)
constexpr int ZROW = 132;           // padded fp32 LDS row for epilogue
constexpr int STG_F16 = CPSG * MTOK * 64;   // 4096 f16 = 8 KB per buffer

// ---- prep: W1|W2 -> f16 hi / lo*2^11 planes in MFMA B-fragment order (unchanged).
__global__ void prep_w(const float* __restrict__ W1, const float* __restrict__ W2,
                       _Float16* __restrict__ wt3) {
    const int g    = blockIdx.x * 256 + threadIdx.x;   // 0..32767
    const int cg   = g >> 9;
    const int rem  = g & 511;
    const int t    = rem >> 6;
    const int lane = rem & 63;
    const int col  = lane & 15, q = lane >> 4;
    const int n    = t * 16 + col;
    const float* W = (t < 4) ? W1 : W2;
    const int cn   = n & 63;
    _Float16 h[8], l[8];
    #pragma unroll
    for (int j = 0; j < 8; ++j) {
        const float v = W[(size_t)(cg * 32 + q * 8 + j) * 64 + cn];
        const _Float16 hh = (_Float16)v;
        h[j] = hh;
        l[j] = (_Float16)((v - (float)hh) * 2048.0f);
    }
    *(f16x8*)&wt3[((size_t)(cg * 2 + 0) * 8 + t) * 512 + lane * 8] = *(f16x8*)h;
    *(f16x8*)&wt3[((size_t)(cg * 2 + 1) * 8 + t) * 512 + lane * 8] = *(f16x8*)l;
}

__device__ __forceinline__ void split4(const float4 v, f16x4& hh, f16x4& ll) {
    const _Float16 h0 = (_Float16)v.x, h1 = (_Float16)v.y,
                   h2 = (_Float16)v.z, h3 = (_Float16)v.w;
    hh = (f16x4){h0, h1, h2, h3};
    ll = (f16x4){(_Float16)((v.x - (float)h0) * 2048.0f),
                 (_Float16)((v.y - (float)h1) * 2048.0f),
                 (_Float16)((v.z - (float)h2) * 2048.0f),
                 (_Float16)((v.w - (float)h3) * 2048.0f)};
}

// non-draining block barrier: LDS ordering only; vmcnt stays counted.
__device__ __forceinline__ void block_sync_lds() {
    asm volatile("s_waitcnt lgkmcnt(0)" ::: "memory");
    __builtin_amdgcn_s_barrier();
}

__global__ __launch_bounds__(256, 4)
void router_fused(const float* __restrict__ x, const _Float16* __restrict__ wt3,
                  const float* __restrict__ noise,
                  const float* __restrict__ b1, const float* __restrict__ b2,
                  float* __restrict__ out_sparse, float* __restrict__ out_idx,
                  float* __restrict__ out_full) {
    __shared__ __align__(16) _Float16 stage[2][STG_F16];   // 16 KB total
    const int tid  = threadIdx.x;
    const int lane = tid & 63;
    const int wu   = __builtin_amdgcn_readfirstlane(tid >> 6);
    const int col  = lane & 15, q = lane >> 4;   // col = token 0..15
    const long tok0 = (long)blockIdx.x * MTOK;
    const int ta = 2 * wu, tb = 2 * wu + 1;   // this wave's N-tiles

    // staging map: 16 threads/token; thread's j-th float4 (j=0,1) covers
    // chunk cc = j*2 + (fsub>>3), k-group g = fsub&7 (k = g*4..g*4+3).
    const int stok = tid >> 4, fsub = tid & 15;
    const float* xs = x + (tok0 + stok) * (size_t)ND + fsub * 4;
    const int g8 = fsub & 7;
    const int wS = g8 >> 1, wh = g8 & 1;

    const _Float16* wla = wt3 + (size_t)ta * 512 + (size_t)lane * 8;
    const _Float16* wlb = wt3 + (size_t)tb * 512 + (size_t)lane * 8;

    f32x4 a0[2], a1[2], zk0[2];
    #pragma unroll
    for (int i = 0; i < 2; ++i)
        #pragma unroll
        for (int r = 0; r < 4; ++r) { a0[i][r] = 0.f; a1[i][r] = 0.f; }

    auto loadX = [&](float4 (&xr)[2], const int s) {
        #pragma unroll
        for (int j = 0; j < 2; ++j)
            xr[j] = *(const float4*)(xs + (size_t)s * 128 + (size_t)j * 64);
    };
    auto deposit = [&](_Float16* wb, const float4 (&xr)[2]) {
        #pragma unroll
        for (int j = 0; j < 2; ++j) {
            const int cc = j * 2 + (fsub >> 3);
            f16x4 hv, lv; split4(xr[j], hv, lv);
            const int idx = ((cc * MTOK + stok) << 6)
                          + (((wS ^ (stok & 7) ^ ((cc & 1) << 2)) << 3) + (wh << 2));
            *(f16x4*)&wb[idx]      = hv;
            *(f16x4*)&wb[idx ^ 32] = lv;
        }
    };

    // one stage: issue B (two halves), issue x(s+1) last (newest -> B waits
    // exclude it), 4 chunks of ds_read A + 6 MFMA, fold at HSTG-1, deposit,
    // non-draining barrier. TLP (16 waves/CU) hides the counted vmcnt waits.
    auto do_stage = [&](const int s, const _Float16* rb, _Float16* wb) {
        f16x8 B[CPSG][4];
        #pragma unroll
        for (int cc = 0; cc < 2; ++cc) {   // first half
            const size_t cb = (size_t)(s * CPSG + cc) * 8192;
            B[cc][0] = *(const f16x8*)(wla + cb);
            B[cc][1] = *(const f16x8*)(wlb + cb);
            B[cc][2] = *(const f16x8*)(wla + cb + 4096);
            B[cc][3] = *(const f16x8*)(wlb + cb + 4096);
        }
        #pragma unroll
        for (int cc = 2; cc < CPSG; ++cc) {   // second half
            const size_t cb = (size_t)(s * CPSG + cc) * 8192;
            B[cc][0] = *(const f16x8*)(wla + cb);
            B[cc][1] = *(const f16x8*)(wlb + cb);
            B[cc][2] = *(const f16x8*)(wla + cb + 4096);
            B[cc][3] = *(const f16x8*)(wlb + cb + 4096);
        }
        float4 xl[2];
        if (s + 1 < NSTG) loadX(xl, s + 1);
        #pragma unroll
        for (int cc = 0; cc < CPSG; ++cc) {
            const int swz = (cc & 1) << 2;
            const int ridx = ((cc * MTOK + col) << 6)
                           + ((q ^ (col & 7) ^ swz) << 3);
            const f16x8 ah = *(const f16x8*)&rb[ridx];
            const f16x8 al = *(const f16x8*)&rb[ridx ^ 32];
            // per-accumulator chain order identical to R6..R10
            a0[0] = __builtin_amdgcn_mfma_f32_16x16x32_f16(ah, B[cc][0], a0[0], 0, 0, 0);
            a0[1] = __builtin_amdgcn_mfma_f32_16x16x32_f16(ah, B[cc][1], a0[1], 0, 0, 0);
            a1[0] = __builtin_amdgcn_mfma_f32_16x16x32_f16(ah, B[cc][2], a1[0], 0, 0, 0);
            a1[1] = __builtin_amdgcn_mfma_f32_16x16x32_f16(ah, B[cc][3], a1[1], 0, 0, 0);
            a1[0] = __builtin_amdgcn_mfma_f32_16x16x32_f16(al, B[cc][0], a1[0], 0, 0, 0);
            a1[1] = __builtin_amdgcn_mfma_f32_16x16x32_f16(al, B[cc][1], a1[1], 0, 0, 0);
        }
        if (s == HSTG - 1) {   // chunks 0..31 done: fold seg-0 partial, reset acc
            #pragma unroll
            for (int i = 0; i < 2; ++i) {
                zk0[i] = a0[i] + a1[i] * 4.8828125e-4f;
                #pragma unroll
                for (int r = 0; r < 4; ++r) { a0[i][r] = 0.f; a1[i][r] = 0.f; }
            }
        }
        if (s + 1 < NSTG) deposit(wb, xl);
        block_sync_lds();
    };

    // prologue: stage-0 deposit
    {
        float4 x0[2];
        loadX(x0, 0);
        deposit(stage[0], x0);
    }
    block_sync_lds();

    // main loop, unrolled x2: buffers compile-time
    for (int sp = 0; sp < NSTG; sp += 2) {
        do_stage(sp,     stage[0], stage[1]);
        do_stage(sp + 1, stage[1], stage[0]);
    }

    // seg-1 fold + f64 combine, stage z-tile to LDS (aliases stage bufs; all
    // frag reads completed at the final stage barrier).
    float* zs = (float*)&stage[0][0];   // 16*132*4 = 8448 B <= 16 KB
    #pragma unroll
    for (int i = 0; i < 2; ++i) {
        const int n = (ta + i) * 16 + col;
        #pragma unroll
        for (int r = 0; r < 4; ++r) {
            const float zk1 = a0[i][r] + a1[i][r] * 4.8828125e-4f;
            const float comb = (float)((double)zk0[i][r] + (double)zk1);
            zs[(q * 4 + r) * ZROW + n] = comb;
        }
    }
    __syncthreads();

    // ---- epilogue: softplus, softmax/top8/masked softmax (verbatim; 4 tok/wave).
    const float b1v = b1[lane];
    const float b2v = b2[lane];
    for (int tt = 0; tt < 4; ++tt) {
        const int lt = wu * 4 + tt;
        const long tok = tok0 + lt;
        const float z1 = zs[lt * ZROW + lane] + b1v;
        const float z2 = zs[lt * ZROW + 64 + lane] + b2v;
        const float sc = (float)log1p(exp((double)z2));   // f64 softplus
        const float nz = noise[tok * NE + lane];
        const float mixed = z1 + nz * sc;

        float vmax = mixed;
        for (int off = 32; off; off >>= 1) vmax = fmaxf(vmax, __shfl_xor(vmax, off));
        const float e = expf(mixed - vmax);
        float denom = e;
        for (int off = 32; off; off >>= 1) denom += __shfl_xor(denom, off);
        const float fullv = e / denom;

        float cur = mixed;
        int   sel = 0;
        float myidxf = 0.0f;
        #pragma unroll
        for (int r = 0; r < NK; ++r) {
            float bv = cur; int bi = lane;
            for (int off = 32; off; off >>= 1) {
                const float ov = __shfl_xor(bv, off);
                const int   oi = __shfl_xor(bi, off);
                if (ov > bv || (ov == bv && oi < bi)) { bv = ov; bi = oi; }
            }
            if (lane == r)  myidxf = (float)bi;
            if (lane == bi) { sel = 1; cur = -INFINITY; }
        }

        const float es = sel ? e : 0.0f;
        float dsum = es;
        for (int off = 32; off; off >>= 1) dsum += __shfl_xor(dsum, off);
        const float sparsev = sel ? (e / dsum) : 0.0f;

        out_full[tok * NE + lane]   = fullv;
        out_sparse[tok * NE + lane] = sparsev;
        if (lane < NK) out_idx[tok * NK + lane] = myidxf;
    }
}

extern "C" void kernel_launch(void* const* d_in, const int* in_sizes, int n_in,
                              void* d_out, int out_size, void* d_ws, size_t ws_size,
                              hipStream_t stream) {
    const float* x     = (const float*)d_in[0];
    const float* noise = (const float*)d_in[1];
    const float* W1    = (const float*)d_in[2];
    const float* b1    = (const float*)d_in[3];
    const float* W2    = (const float*)d_in[4];
    const float* b2    = (const float*)d_in[5];

    float* out_sparse = (float*)d_out;                      // [16384*64]
    float* out_idx    = out_sparse + (size_t)NTOK * NE;     // [16384*8]
    float* out_full   = out_idx + (size_t)NTOK * NK;        // [16384*64]

    _Float16* wt3 = (_Float16*)d_ws;                        // 1 MB fragment-order W

    prep_w<<<128, 256, 0, stream>>>(W1, W2, wt3);
    router_fused<<<NTOK / MTOK, 256, 0, stream>>>(x, wt3, noise, b1, b2,
                                                  out_sparse, out_idx, out_full);   // 1024 blocks
}